// Round 15
// baseline (31.014 us; speedup 1.0000x reference)
//
#include <hip/hip_runtime.h>
#include <math.h>

#define NM    4096          // output modes
#define HALFN 2048
#define MR    8192          // oversampled grid (2x)
#define MRM   (MR - 1)
#define STPB  512           // spread threads per block
#define NP    256           // partial grids (fixed: tiled layout hardcodes it)
#define W     6             // Gaussian taps (E = 6.66, err ~1.3e-3 rel)
#define FSCALE 65536.0f     // fixed-point scale 2^16
#define INVFS  (1.0f / 65536.0f)
#define SW(m) ((m) + ((m) >> 6))    // LDS swizzle: stride-64 column -> stride-65
#define LDSN  (MR + MR / 64)        // 8320 ints per component
#define PIM_OFF 2097152             // ints: Pim base (= 64*256*128)
#define Y_OFF   4194304             // floats: Y base (= 2*PIM_OFF)

// hw trig/exp: v_sin/v_cos take REVOLUTIONS; v_exp_f32 computes 2^x.
__device__ __forceinline__ float sin2pi(float r) {
    float o; asm volatile("v_sin_f32 %0, %1" : "=v"(o) : "v"(r)); return o;
}
__device__ __forceinline__ float cos2pi(float r) {
    float o; asm volatile("v_cos_f32 %0, %1" : "=v"(o) : "v"(r)); return o;
}
__device__ __forceinline__ float exp2a(float x) {
    float o; asm volatile("v_exp_f32 %0, %1" : "=v"(o) : "v"(x)); return o;
}

// ---------------- 1) spread: points -> swizzled LDS int grid -> tiled partials
// Partial layout (ints): Pre[(n2*256 + p)*128 + n1] for grid bin m = n1*64+n2,
// Pim at +PIM_OFF. Block p's chunk for each n2 is 128 consecutive ints ->
// coalesced writeback AND contiguous per-n2 reads in fft1.
__global__ __launch_bounds__(STPB) void nufft_spread(
    const float* __restrict__ pts, const float* __restrict__ vre,
    const float* __restrict__ vim, float* __restrict__ ws,
    int M, int ppb, float nalpha, float4 cA, float2 cB)
{
    __shared__ int gre[LDSN];
    __shared__ int gim[LDSN];
    const int tid = threadIdx.x;
    const int p   = blockIdx.x;
    const float C[W] = {cA.x, cA.y, cA.z, cA.w, cB.x, cB.y};

    for (int i = tid; i < LDSN; i += STPB) { gre[i] = 0; gim[i] = 0; }
    __syncthreads();

    const int j0   = p * ppb;
    const int jend = min(j0 + ppb, M);
    const float inv2pi = 0.15915494309189535f;

    for (int j = j0 + tid; j < jend; j += STPB) {
        float x  = pts[j];
        float cr = vre[j];
        float ci = vim[j];
        float u = x * inv2pi;
        u -= floorf(u);                 // [0,1)
        float pp = u * (float)MR;       // grid position [0, 8192]
        float fl = floorf(pp);
        int   i0 = (int)fl - 2;
        float t0 = (fl - pp) - 2.0f;    // m - p for m = i0, in (-3, -2]
        float E1 = exp2a(nalpha * t0 * t0);      // exp(-alpha*t0^2)
        float r  = exp2a(2.0f * nalpha * t0);    // exp(-2*alpha*t0)
        float crs = cr * FSCALE * E1;
        float cis = ci * FSCALE * E1;
        float w = 1.0f;
#pragma unroll
        for (int i = 0; i < W; ++i) {
            float wgt = w * C[i];
            int m = (i0 + i) & MRM;
            int ms = SW(m);
            atomicAdd(&gre[ms], (int)(wgt * crs));   // native ds_add_u32
            atomicAdd(&gim[ms], (int)(wgt * cis));
            w *= r;
        }
    }
    __syncthreads();

    // tiled-transposed writeback: P[(n2*256+p)*128 + n1] = lds[n1*65 + n2]
    // lane-bank = (n1+n2)%32 -> conflict-free; stores 256B-coalesced per wave.
    int* Pre = (int*)ws;
    int* Pim = (int*)ws + PIM_OFF;
    const int n1 = tid & 127, r0 = tid >> 7;
    for (int n2 = r0; n2 < 64; n2 += 4) {
        size_t dst = ((size_t)(n2 * NP + p)) * 128 + n1;
        int li = n1 * 65 + n2;
        Pre[dst] = gre[li];
        Pim[dst] = gim[li];
    }
}

// ---------------- 2) fused reduce + FFT step 1 ------------------------------
// Block b = n2: sums its contiguous 128KB re/im partial chunks (int, exact),
// then 128-pt FFT over n1 (verified round 13) + inter-stage twiddle -> Y.
// Y[k1*64+n2] = e^{+2pi i n2 k1/8192} * sum_n1 x[n1*64+n2] e^{+2pi i n1 k1/128}
__global__ __launch_bounds__(512) void nufft_fft1(float* __restrict__ ws)
{
    __shared__ int bufr[4][128];
    __shared__ int bufi[4][128];
    __shared__ float sre[128];
    __shared__ float sim[128];
    const int tid = threadIdx.x;
    const int b   = blockIdx.x;                      // n2
    const int n1 = tid & 127, q = tid >> 7;

    const int* Pre = (const int*)ws + (size_t)b * (NP * 128);
    const int* Pim = (const int*)ws + PIM_OFF + (size_t)b * (NP * 128);
    int sr = 0, si = 0;
#pragma unroll 16
    for (int pp = 0; pp < 64; ++pp) {
        int off = (q * 64 + pp) * 128 + n1;
        sr += Pre[off];
        si += Pim[off];
    }
    bufr[q][n1] = sr;
    bufi[q][n1] = si;
    __syncthreads();

    if (tid < 128) {
        int tr = bufr[0][n1] + bufr[1][n1] + bufr[2][n1] + bufr[3][n1];
        int ti = bufi[0][n1] + bufi[1][n1] + bufi[2][n1] + bufi[3][n1];
        int rr = __brev((unsigned)n1) >> 25;         // bitrev7
        sre[rr] = (float)tr * INVFS;
        sim[rr] = (float)ti * INVFS;
    }
    __syncthreads();

    for (int half = 1; half < 128; half <<= 1) {
        if (tid < 64) {
            int t  = tid & (half - 1);
            int i0 = ((tid ^ t) << 1) + t;
            float tf = (float)t / (float)(half << 1);
            float wr = cos2pi(tf), wi = sin2pi(tf);  // e^{+2pi i t/len}
            float xr = sre[i0 + half], xi = sim[i0 + half];
            float vr = fmaf(xr, wr, -(xi * wi));
            float vi = fmaf(xr, wi,   xi * wr);
            float ur = sre[i0], ui = sim[i0];
            sre[i0] = ur + vr;         sim[i0] = ui + vi;
            sre[i0 + half] = ur - vr;  sim[i0 + half] = ui - vi;
        }
        __syncthreads();
    }

    if (tid < 128) {
        int k1 = tid;
        float tf = (float)(k1 * b) * (1.0f / 8192.0f);
        float wr = cos2pi(tf), wi = sin2pi(tf);
        float ar = sre[k1], ai = sim[k1];
        float* Y = ws + Y_OFF;
        Y[k1 * 64 + b]      = fmaf(ar, wr, -(ai * wi));
        Y[MR + k1 * 64 + b] = fmaf(ar, wi,   ai * wr);
    }
}

// ---------------- 3) FFT step 2: 128 x 64-pt FFT + deconv + output ----------
// X[k2*128+k1] = sum_n2 Y[k1*64+n2] e^{+2pi i n2 k2/64}; block = k1.
__global__ __launch_bounds__(64) void nufft_fft2(
    const float* __restrict__ ws, float* __restrict__ out,
    int out_size, float sfac, float taul2e)
{
    __shared__ float sre[64];
    __shared__ float sim[64];
    const int tid = threadIdx.x;
    const int b   = blockIdx.x;                      // k1
    const float* Y = ws + Y_OFF;

    int r = __brev((unsigned)tid) >> 26;             // bitrev6
    sre[r] = Y[b * 64 + tid];
    sim[r] = Y[MR + b * 64 + tid];
    __syncthreads();

    for (int half = 1; half < 64; half <<= 1) {
        if (tid < 32) {
            int t  = tid & (half - 1);
            int i0 = ((tid ^ t) << 1) + t;
            float tf = (float)t / (float)(half << 1);
            float wr = cos2pi(tf), wi = sin2pi(tf);
            float xr = sre[i0 + half], xi = sim[i0 + half];
            float vr = fmaf(xr, wr, -(xi * wi));
            float vi = fmaf(xr, wi,   xi * wr);
            float ur = sre[i0], ui = sim[i0];
            sre[i0] = ur + vr;         sim[i0] = ui + vi;
            sre[i0 + half] = ur - vr;  sim[i0 + half] = ui - vi;
        }
        __syncthreads();
    }

    int k2 = tid;
    bool lo = (k2 < 16), hi = (k2 >= 48);
    if (lo || hi) {
        int k8  = k2 * 128 + b;
        int k   = lo ? k8 : k8 - 8192;               // signed mode
        int idx = lo ? k8 : k8 - 4096;               // FFT-order output index
        float kk = (float)k;
        float corr = sfac * exp2a(kk * kk * taul2e);
        float fre = sre[k2] * corr;
        float fim = sim[k2] * corr;
        if (out_size >= 2 * NM) {
            out[idx]      = fre;
            out[NM + idx] = fim;
        } else {
            out[idx] = fre;
        }
    }
}

extern "C" void kernel_launch(void* const* d_in, const int* in_sizes, int n_in,
                              void* d_out, int out_size, void* d_ws, size_t ws_size,
                              hipStream_t stream)
{
    const float* pts = (const float*)d_in[0];
    const float* vre = (const float*)d_in[1];
    const float* vim = (const float*)d_in[2];
    float* out = (float*)d_out;
    float* ws  = (float*)d_ws;
    const int M = in_sizes[0];

    // Gaussian kernel, w=6, balanced: alpha = gam*sqrt(dif)/6, E = 9*alpha = 6.66
    const double PI  = 3.14159265358979323846;
    const double gam = 2.0 * PI / (double)MR;
    const double dif = (double)(MR - HALFN) * (MR - HALFN) - (double)HALFN * HALFN;
    const double alpha = gam * sqrt(dif) / 6.0;
    const double tau = gam * gam / (4.0 * alpha);
    const double L2E = 1.4426950408889634;
    const float nalpha = (float)(-alpha * L2E);                // exp2 scale
    const float sfac   = (float)sqrt(alpha / PI);
    const float taul2e = (float)(tau * L2E);
    float4 cA = make_float4(1.0f, (float)exp(-alpha), (float)exp(-alpha * 4.0),
                            (float)exp(-alpha * 9.0));
    float2 cB = make_float2((float)exp(-alpha * 16.0), (float)exp(-alpha * 25.0));

    int ppb = (M + NP - 1) / NP;

    hipLaunchKernelGGL(nufft_spread, dim3(NP), dim3(STPB), 0, stream,
                       pts, vre, vim, ws, M, ppb, nalpha, cA, cB);
    hipLaunchKernelGGL(nufft_fft1, dim3(64), dim3(512), 0, stream, ws);
    hipLaunchKernelGGL(nufft_fft2, dim3(128), dim3(64), 0, stream,
                       ws, out, out_size, sfac, taul2e);
}

// Round 16
// 30.282 us; speedup vs baseline: 1.0242x; 1.0242x over previous
//
#include <hip/hip_runtime.h>
#include <math.h>

#define NM    4096          // output modes
#define HALFN 2048
#define MR    8192          // oversampled grid (2x)
#define MRM   (MR - 1)
#define STPB  512           // spread threads per block
#define NB    256           // partial grids
#define W     6             // Gaussian taps (E = 6.66, err ~1.3e-3 rel)
#define FSCALE 65536.0f     // fixed-point scale 2^16
#define INVFS  (1.0f / 65536.0f)

// hw trig/exp: v_sin/v_cos take REVOLUTIONS; v_exp_f32 computes 2^x.
__device__ __forceinline__ float sin2pi(float r) {
    float o; asm volatile("v_sin_f32 %0, %1" : "=v"(o) : "v"(r)); return o;
}
__device__ __forceinline__ float cos2pi(float r) {
    float o; asm volatile("v_cos_f32 %0, %1" : "=v"(o) : "v"(r)); return o;
}
__device__ __forceinline__ float exp2a(float x) {
    float o; asm volatile("v_exp_f32 %0, %1" : "=v"(o) : "v"(x)); return o;
}

// ---------------- 1) spread: points -> privatized LDS int grid -> int partials
// ws: [0,16384) floats = final grid G (re|im planar, written by reduce);
//     ints at [16384 + b*16384 ...) = block b partial grid (re|im planar);
//     floats at ws+16384 reused as FFT intermediate Y after fft1 reads... (Y
//     lives at ws+16384 which aliases partial 0 — safe: fft1 reads partials
//     only via G? No: fft1 reads G only; partials are dead after reduce.)
__global__ __launch_bounds__(STPB) void nufft_spread(
    const float* __restrict__ pts, const float* __restrict__ vre,
    const float* __restrict__ vim, float* __restrict__ ws,
    int M, int ppb, float nalpha, float4 cA, float2 cB)
{
    __shared__ int gre[MR];
    __shared__ int gim[MR];
    const int tid = threadIdx.x;
    const int b   = blockIdx.x;
    const float C[W] = {cA.x, cA.y, cA.z, cA.w, cB.x, cB.y};

    for (int i = tid; i < MR; i += STPB) { gre[i] = 0; gim[i] = 0; }
    __syncthreads();

    const int j0   = b * ppb;
    const int jend = min(j0 + ppb, M);
    const float inv2pi = 0.15915494309189535f;

    for (int j = j0 + tid; j < jend; j += STPB) {
        float x  = pts[j];
        float cr = vre[j];
        float ci = vim[j];
        float u = x * inv2pi;
        u -= floorf(u);                 // [0,1)
        float p  = u * (float)MR;       // grid position [0, 8192]
        float fl = floorf(p);
        int   i0 = (int)fl - 2;
        float t0 = (fl - p) - 2.0f;     // m - p for m = i0, in (-3, -2]
        float E1 = exp2a(nalpha * t0 * t0);      // exp(-alpha*t0^2)
        float r  = exp2a(2.0f * nalpha * t0);    // exp(-2*alpha*t0)
        float crs = cr * FSCALE * E1;
        float cis = ci * FSCALE * E1;
        float w = 1.0f;
#pragma unroll
        for (int i = 0; i < W; ++i) {
            float wgt = w * C[i];
            int m = (i0 + i) & MRM;
            atomicAdd(&gre[m], (int)(wgt * crs));   // native ds_add_u32
            atomicAdd(&gim[m], (int)(wgt * cis));
            w *= r;
        }
    }
    __syncthreads();

    // raw int writeback, vectorized
    int4* buf = (int4*)((int*)ws + 16384 + (size_t)b * 16384);
    const int4* g4r = (const int4*)gre;
    const int4* g4i = (const int4*)gim;
    for (int i = tid; i < MR / 4; i += STPB) {
        buf[i]          = g4r[i];
        buf[MR / 4 + i] = g4i[i];
    }
}

// ---------------- 2) reduce int partials -> float grid G --------------------
// 256 blocks x 64 threads; block owns 16 int4-columns. Lane layout sub-major:
// lanes 0-15 read 256B contiguous (full-line coalescing), 4 partial-quarters
// per column summed via fixed-order LDS combine (int = bit-deterministic).
// int4 loads x unroll 8 => 2 MB in flight across the grid.
__global__ __launch_bounds__(64) void nufft_reduce_grid(
    float* __restrict__ ws, int nb)
{
    const int t    = threadIdx.x;
    const int c    = t & 15;                   // local int4-column
    const int sub  = t >> 4;                   // partial quarter [0,4)
    const int col4 = blockIdx.x * 16 + c;      // [0, 4096)
    const int per  = nb >> 2;
    const int4* P = (const int4*)((const int*)ws + 16384);

    int4 s = make_int4(0, 0, 0, 0);
#pragma unroll 8
    for (int pp = 0; pp < per; ++pp) {
        int4 v = P[(size_t)(sub * per + pp) * 4096 + col4];
        s.x += v.x; s.y += v.y; s.z += v.z; s.w += v.w;
    }
    __shared__ int4 buf[64];
    buf[t] = s;
    __syncthreads();
    if (sub == 0) {
        int4 a = buf[c], b1 = buf[16 + c], b2 = buf[32 + c], b3 = buf[48 + c];
        float4 g;
        g.x = (float)(a.x + b1.x + b2.x + b3.x) * INVFS;
        g.y = (float)(a.y + b1.y + b2.y + b3.y) * INVFS;
        g.z = (float)(a.z + b1.z + b2.z + b3.z) * INVFS;
        g.w = (float)(a.w + b1.w + b2.w + b3.w) * INVFS;
        ((float4*)ws)[col4] = g;
    }
}

// ---------------- 3) FFT step 1: 64 x 128-pt FFT over n1 + twiddle ----------
// x[n], n = n1*64 + n2; block b = n2. (HW-verified rounds 13/14.)
// Y[k1*64+n2] = e^{+2pi i n2 k1/8192} * sum_n1 x[n1*64+n2] e^{+2pi i n1 k1/128}
__global__ __launch_bounds__(128) void nufft_fft1(float* __restrict__ ws)
{
    __shared__ float sre[128];
    __shared__ float sim[128];
    const int tid = threadIdx.x;
    const int b   = blockIdx.x;                      // n2
    const float* Gf = ws;

    int r = __brev((unsigned)tid) >> 25;             // bitrev7
    sre[r] = Gf[tid * 64 + b];
    sim[r] = Gf[MR + tid * 64 + b];
    __syncthreads();

    for (int half = 1; half < 128; half <<= 1) {
        if (tid < 64) {
            int t  = tid & (half - 1);
            int i0 = ((tid ^ t) << 1) + t;
            float tf = (float)t / (float)(half << 1);
            float wr = cos2pi(tf), wi = sin2pi(tf);  // e^{+2pi i t/len}
            float xr = sre[i0 + half], xi = sim[i0 + half];
            float vr = fmaf(xr, wr, -(xi * wi));
            float vi = fmaf(xr, wi,   xi * wr);
            float ur = sre[i0], ui = sim[i0];
            sre[i0] = ur + vr;         sim[i0] = ui + vi;
            sre[i0 + half] = ur - vr;  sim[i0 + half] = ui - vi;
        }
        __syncthreads();
    }

    int k1 = tid;
    float tf = (float)(k1 * b) * (1.0f / 8192.0f);
    float wr = cos2pi(tf), wi = sin2pi(tf);
    float ar = sre[k1], ai = sim[k1];
    float* Y = ws + 16384;
    Y[k1 * 64 + b]      = fmaf(ar, wr, -(ai * wi));
    Y[MR + k1 * 64 + b] = fmaf(ar, wi,   ai * wr);
}

// ---------------- 4) FFT step 2: 128 x 64-pt FFT + deconv + output ----------
// X[k2*128+k1] = sum_n2 Y[k1*64+n2] e^{+2pi i n2 k2/64}; block = k1.
__global__ __launch_bounds__(64) void nufft_fft2(
    const float* __restrict__ ws, float* __restrict__ out,
    int out_size, float sfac, float taul2e)
{
    __shared__ float sre[64];
    __shared__ float sim[64];
    const int tid = threadIdx.x;
    const int b   = blockIdx.x;                      // k1
    const float* Y = ws + 16384;

    int r = __brev((unsigned)tid) >> 26;             // bitrev6
    sre[r] = Y[b * 64 + tid];
    sim[r] = Y[MR + b * 64 + tid];
    __syncthreads();

    for (int half = 1; half < 64; half <<= 1) {
        if (tid < 32) {
            int t  = tid & (half - 1);
            int i0 = ((tid ^ t) << 1) + t;
            float tf = (float)t / (float)(half << 1);
            float wr = cos2pi(tf), wi = sin2pi(tf);
            float xr = sre[i0 + half], xi = sim[i0 + half];
            float vr = fmaf(xr, wr, -(xi * wi));
            float vi = fmaf(xr, wi,   xi * wr);
            float ur = sre[i0], ui = sim[i0];
            sre[i0] = ur + vr;         sim[i0] = ui + vi;
            sre[i0 + half] = ur - vr;  sim[i0 + half] = ui - vi;
        }
        __syncthreads();
    }

    int k2 = tid;
    bool lo = (k2 < 16), hi = (k2 >= 48);
    if (lo || hi) {
        int k8  = k2 * 128 + b;
        int k   = lo ? k8 : k8 - 8192;               // signed mode
        int idx = lo ? k8 : k8 - 4096;               // FFT-order output index
        float kk = (float)k;
        float corr = sfac * exp2a(kk * kk * taul2e);
        float fre = sre[k2] * corr;
        float fim = sim[k2] * corr;
        if (out_size >= 2 * NM) {
            out[idx]      = fre;
            out[NM + idx] = fim;
        } else {
            out[idx] = fre;
        }
    }
}

extern "C" void kernel_launch(void* const* d_in, const int* in_sizes, int n_in,
                              void* d_out, int out_size, void* d_ws, size_t ws_size,
                              hipStream_t stream)
{
    const float* pts = (const float*)d_in[0];
    const float* vre = (const float*)d_in[1];
    const float* vim = (const float*)d_in[2];
    float* out = (float*)d_out;
    float* ws  = (float*)d_ws;
    const int M = in_sizes[0];

    // Gaussian kernel, w=6, balanced: alpha = gam*sqrt(dif)/6, E = 9*alpha = 6.66
    const double PI  = 3.14159265358979323846;
    const double gam = 2.0 * PI / (double)MR;
    const double dif = (double)(MR - HALFN) * (MR - HALFN) - (double)HALFN * HALFN;
    const double alpha = gam * sqrt(dif) / 6.0;
    const double tau = gam * gam / (4.0 * alpha);
    const double L2E = 1.4426950408889634;
    const float nalpha = (float)(-alpha * L2E);                // exp2 scale
    const float sfac   = (float)sqrt(alpha / PI);
    const float taul2e = (float)(tau * L2E);
    float4 cA = make_float4(1.0f, (float)exp(-alpha), (float)exp(-alpha * 4.0),
                            (float)exp(-alpha * 9.0));
    float2 cB = make_float2((float)exp(-alpha * 16.0), (float)exp(-alpha * 25.0));

    int nb = NB;
    while (nb > 4 && (size_t)(nb + 1) * 65536 > ws_size) nb >>= 1;
    int ppb = (M + nb - 1) / nb;

    hipLaunchKernelGGL(nufft_spread, dim3(nb), dim3(STPB), 0, stream,
                       pts, vre, vim, ws, M, ppb, nalpha, cA, cB);
    hipLaunchKernelGGL(nufft_reduce_grid, dim3(nb), dim3(64), 0, stream, ws, nb);
    hipLaunchKernelGGL(nufft_fft1, dim3(64), dim3(128), 0, stream, ws);
    hipLaunchKernelGGL(nufft_fft2, dim3(128), dim3(64), 0, stream,
                       ws, out, out_size, sfac, taul2e);
}

// Round 17
// 28.836 us; speedup vs baseline: 1.0755x; 1.0501x over previous
//
#include <hip/hip_runtime.h>
#include <math.h>

#define NM    4096          // output modes
#define HALFN 2048
#define MR    8192          // oversampled grid (2x)
#define MRM   (MR - 1)
#define STPB  512           // spread threads per block
#define NB    256           // partial grids
#define W     6             // Gaussian taps (E = 6.66, err ~1.3e-3 rel)
#define FSCALE 65536.0f     // fixed-point scale 2^16
#define INVFS  (1.0f / 65536.0f)

// hw trig/exp: v_sin/v_cos take REVOLUTIONS; v_exp_f32 computes 2^x.
__device__ __forceinline__ float sin2pi(float r) {
    float o; asm volatile("v_sin_f32 %0, %1" : "=v"(o) : "v"(r)); return o;
}
__device__ __forceinline__ float cos2pi(float r) {
    float o; asm volatile("v_cos_f32 %0, %1" : "=v"(o) : "v"(r)); return o;
}
__device__ __forceinline__ float exp2a(float x) {
    float o; asm volatile("v_exp_f32 %0, %1" : "=v"(o) : "v"(x)); return o;
}

// ---------------- 1) spread: points -> privatized LDS int grid -> int partials
// ws (ints): [0,16384) = final grid G (re|im planar);
//            [16384 + b*16384 ...) = block b partial grid;
// floats at ws+16384 are reused as FFT intermediate Y after the reduce.
__global__ __launch_bounds__(STPB) void nufft_spread(
    const float* __restrict__ pts, const float* __restrict__ vre,
    const float* __restrict__ vim, float* __restrict__ ws,
    int M, int ppb, float nalpha, float4 cA, float2 cB)
{
    __shared__ int gre[MR];
    __shared__ int gim[MR];
    const int tid = threadIdx.x;
    const int b   = blockIdx.x;
    const float C[W] = {cA.x, cA.y, cA.z, cA.w, cB.x, cB.y};

    for (int i = tid; i < MR; i += STPB) { gre[i] = 0; gim[i] = 0; }
    __syncthreads();

    const int j0   = b * ppb;
    const int jend = min(j0 + ppb, M);
    const float inv2pi = 0.15915494309189535f;

    for (int j = j0 + tid; j < jend; j += STPB) {
        float x  = pts[j];
        float cr = vre[j];
        float ci = vim[j];
        float u = x * inv2pi;
        u -= floorf(u);                 // [0,1)
        float p  = u * (float)MR;       // grid position [0, 8192]
        float fl = floorf(p);
        int   i0 = (int)fl - 2;
        float t0 = (fl - p) - 2.0f;     // m - p for m = i0, in (-3, -2]
        float E1 = exp2a(nalpha * t0 * t0);      // exp(-alpha*t0^2)
        float r  = exp2a(2.0f * nalpha * t0);    // exp(-2*alpha*t0)
        float crs = cr * FSCALE * E1;
        float cis = ci * FSCALE * E1;
        float w = 1.0f;
#pragma unroll
        for (int i = 0; i < W; ++i) {
            float wgt = w * C[i];
            int m = (i0 + i) & MRM;
            atomicAdd(&gre[m], (int)(wgt * crs));   // native ds_add_u32
            atomicAdd(&gim[m], (int)(wgt * cis));
            w *= r;
        }
    }
    __syncthreads();

    // raw int writeback, vectorized
    int4* buf = (int4*)((int*)ws + 16384 + (size_t)b * 16384);
    const int4* g4r = (const int4*)gre;
    const int4* g4i = (const int4*)gim;
    for (int i = tid; i < MR / 4; i += STPB) {
        buf[i]          = g4r[i];
        buf[MR / 4 + i] = g4i[i];
    }
}

// ---------------- 2) reduce int partials -> int grid G ----------------------
// 16384 threads, one int column each, coalesced; unroll 32 => 2 MB in flight.
__global__ __launch_bounds__(64) void nufft_reduce_grid(
    float* __restrict__ ws, int nb)
{
    int i = blockIdx.x * 64 + threadIdx.x;           // [0, 16384)
    const int* src = (const int*)ws + 16384 + i;
    int s = 0;
#pragma unroll 32
    for (int b = 0; b < nb; ++b) s += src[(size_t)b * 16384];
    ((int*)ws)[i] = s;
}

// ---------------- 3) FFT step 1: 64 x 128-pt FFT over n1 + twiddle ----------
// x[n], n = n1*64 + n2; block b = n2. (Verified rounds 13/14.)
// Y[k1*64+n2] = e^{+2pi i n2 k1/8192} * sum_n1 x[n1*64+n2] e^{+2pi i n1 k1/128}
__global__ __launch_bounds__(128) void nufft_fft1(float* __restrict__ ws)
{
    __shared__ float sre[128];
    __shared__ float sim[128];
    const int tid = threadIdx.x;
    const int b   = blockIdx.x;                      // n2
    const int* Gi = (const int*)ws;

    int r = __brev((unsigned)tid) >> 25;             // bitrev7
    sre[r] = (float)Gi[tid * 64 + b]      * INVFS;
    sim[r] = (float)Gi[MR + tid * 64 + b] * INVFS;
    __syncthreads();

    for (int half = 1; half < 128; half <<= 1) {
        if (tid < 64) {
            int t  = tid & (half - 1);
            int i0 = ((tid ^ t) << 1) + t;
            float tf = (float)t / (float)(half << 1);
            float wr = cos2pi(tf), wi = sin2pi(tf);  // e^{+2pi i t/len}
            float xr = sre[i0 + half], xi = sim[i0 + half];
            float vr = fmaf(xr, wr, -(xi * wi));
            float vi = fmaf(xr, wi,   xi * wr);
            float ur = sre[i0], ui = sim[i0];
            sre[i0] = ur + vr;         sim[i0] = ui + vi;
            sre[i0 + half] = ur - vr;  sim[i0 + half] = ui - vi;
        }
        __syncthreads();
    }

    int k1 = tid;
    float tf = (float)(k1 * b) * (1.0f / 8192.0f);
    float wr = cos2pi(tf), wi = sin2pi(tf);
    float ar = sre[k1], ai = sim[k1];
    float* Y = ws + 16384;
    Y[k1 * 64 + b]      = fmaf(ar, wr, -(ai * wi));
    Y[MR + k1 * 64 + b] = fmaf(ar, wi,   ai * wr);
}

// ---------------- 4) FFT step 2: 128 x 64-pt FFT + deconv + output ----------
// X[k2*128+k1] = sum_n2 Y[k1*64+n2] e^{+2pi i n2 k2/64}; block = k1.
// (Verified rounds 13/14.)
__global__ __launch_bounds__(64) void nufft_fft2(
    const float* __restrict__ ws, float* __restrict__ out,
    int out_size, float sfac, float taul2e)
{
    __shared__ float sre[64];
    __shared__ float sim[64];
    const int tid = threadIdx.x;
    const int b   = blockIdx.x;                      // k1
    const float* Y = ws + 16384;

    int r = __brev((unsigned)tid) >> 26;             // bitrev6
    sre[r] = Y[b * 64 + tid];
    sim[r] = Y[MR + b * 64 + tid];
    __syncthreads();

    for (int half = 1; half < 64; half <<= 1) {
        if (tid < 32) {
            int t  = tid & (half - 1);
            int i0 = ((tid ^ t) << 1) + t;
            float tf = (float)t / (float)(half << 1);
            float wr = cos2pi(tf), wi = sin2pi(tf);
            float xr = sre[i0 + half], xi = sim[i0 + half];
            float vr = fmaf(xr, wr, -(xi * wi));
            float vi = fmaf(xr, wi,   xi * wr);
            float ur = sre[i0], ui = sim[i0];
            sre[i0] = ur + vr;         sim[i0] = ui + vi;
            sre[i0 + half] = ur - vr;  sim[i0 + half] = ui - vi;
        }
        __syncthreads();
    }

    int k2 = tid;
    bool lo = (k2 < 16), hi = (k2 >= 48);
    if (lo || hi) {
        int k8  = k2 * 128 + b;
        int k   = lo ? k8 : k8 - 8192;               // signed mode
        int idx = lo ? k8 : k8 - 4096;               // FFT-order output index
        float kk = (float)k;
        float corr = sfac * exp2a(kk * kk * taul2e);
        float fre = sre[k2] * corr;
        float fim = sim[k2] * corr;
        if (out_size >= 2 * NM) {
            out[idx]      = fre;
            out[NM + idx] = fim;
        } else {
            out[idx] = fre;
        }
    }
}

extern "C" void kernel_launch(void* const* d_in, const int* in_sizes, int n_in,
                              void* d_out, int out_size, void* d_ws, size_t ws_size,
                              hipStream_t stream)
{
    const float* pts = (const float*)d_in[0];
    const float* vre = (const float*)d_in[1];
    const float* vim = (const float*)d_in[2];
    float* out = (float*)d_out;
    float* ws  = (float*)d_ws;
    const int M = in_sizes[0];

    // Gaussian kernel, w=6, balanced: alpha = gam*sqrt(dif)/6, E = 9*alpha = 6.66
    const double PI  = 3.14159265358979323846;
    const double gam = 2.0 * PI / (double)MR;
    const double dif = (double)(MR - HALFN) * (MR - HALFN) - (double)HALFN * HALFN;
    const double alpha = gam * sqrt(dif) / 6.0;
    const double tau = gam * gam / (4.0 * alpha);
    const double L2E = 1.4426950408889634;
    const float nalpha = (float)(-alpha * L2E);                // exp2 scale
    const float sfac   = (float)sqrt(alpha / PI);
    const float taul2e = (float)(tau * L2E);
    float4 cA = make_float4(1.0f, (float)exp(-alpha), (float)exp(-alpha * 4.0),
                            (float)exp(-alpha * 9.0));
    float2 cB = make_float2((float)exp(-alpha * 16.0), (float)exp(-alpha * 25.0));

    int nb = NB;
    while (nb > 1 && (size_t)(nb + 1) * 65536 > ws_size) nb >>= 1;
    int ppb = (M + nb - 1) / nb;

    hipLaunchKernelGGL(nufft_spread, dim3(nb), dim3(STPB), 0, stream,
                       pts, vre, vim, ws, M, ppb, nalpha, cA, cB);
    hipLaunchKernelGGL(nufft_reduce_grid, dim3(256), dim3(64), 0, stream, ws, nb);
    hipLaunchKernelGGL(nufft_fft1, dim3(64), dim3(128), 0, stream, ws);
    hipLaunchKernelGGL(nufft_fft2, dim3(128), dim3(64), 0, stream,
                       ws, out, out_size, sfac, taul2e);
}